// Round 1
// baseline (1015.102 us; speedup 1.0000x reference)
//
#include <hip/hip_runtime.h>

#define SEQ 2048
#define BB 4
#define DM 1024
#define NH 16
#define DH 64
#define ROWS (BB*SEQ)

typedef _Float16 f16;
typedef _Float16 f16x8 __attribute__((ext_vector_type(8)));
typedef _Float16 f16x4 __attribute__((ext_vector_type(4)));
typedef float f32x4 __attribute__((ext_vector_type(4)));

__device__ __forceinline__ f32x4 mfma16(f16x8 a, f16x8 b, f32x4 c) {
    return __builtin_amdgcn_mfma_f32_16x16x32_f16(a, b, c, 0, 0, 0);
}

// ---------------- weight conversion fp32 -> f16 ----------------
__global__ __launch_bounds__(256) void cvt_weights(
    const float* __restrict__ wq, const float* __restrict__ wk,
    const float* __restrict__ wv, const float* __restrict__ wo,
    f16* __restrict__ oq, f16* __restrict__ ok,
    f16* __restrict__ ov, f16* __restrict__ oo) {
    int i = (blockIdx.x * 256 + threadIdx.x) * 4;
    float4 a = *(const float4*)(wq + i);
    float4 b = *(const float4*)(wk + i);
    float4 c = *(const float4*)(wv + i);
    float4 d = *(const float4*)(wo + i);
    f16x4 va = { (f16)a.x, (f16)a.y, (f16)a.z, (f16)a.w };
    f16x4 vb = { (f16)b.x, (f16)b.y, (f16)b.z, (f16)b.w };
    f16x4 vc = { (f16)c.x, (f16)c.y, (f16)c.z, (f16)c.w };
    f16x4 vd = { (f16)d.x, (f16)d.y, (f16)d.z, (f16)d.w };
    *(f16x4*)(oq + i) = va;
    *(f16x4*)(ok + i) = vb;
    *(f16x4*)(ov + i) = vc;
    *(f16x4*)(oo + i) = vd;
}

// ---------------- QKV projection GEMM ----------------
// out[s][n] = (sum_k X[s][k] * W[n][k] + bias[n]) * scale
// mode 0: write [b][h][s][dh]   (q, k)
// mode 2: write [b][h][dh][s]   (v transposed)
__global__ __launch_bounds__(256) void proj_kernel(
    const float* __restrict__ X, const f16* __restrict__ W,
    const float* __restrict__ bias, f16* __restrict__ out,
    float scale, int mode) {
    const int lane = threadIdx.x & 63;
    const int wave = threadIdx.x >> 6;
    const int lo = lane & 15, hi = lane >> 4;
    const int rowbase = blockIdx.x * 64 + wave * 16;
    const int colbase = blockIdx.y * 256;

    f32x4 acc[16];
#pragma unroll
    for (int t = 0; t < 16; ++t) acc[t] = (f32x4){0.f, 0.f, 0.f, 0.f};

    const float* ap = X + (size_t)(rowbase + lo) * DM + hi * 8;
    for (int k0 = 0; k0 < DM; k0 += 32) {
        float4 a0 = *(const float4*)(ap);
        float4 a1 = *(const float4*)(ap + 4);
        ap += 32;
        f16x8 a;
        a[0] = (f16)a0.x; a[1] = (f16)a0.y; a[2] = (f16)a0.z; a[3] = (f16)a0.w;
        a[4] = (f16)a1.x; a[5] = (f16)a1.y; a[6] = (f16)a1.z; a[7] = (f16)a1.w;
        const f16* wp = W + (size_t)(colbase + lo) * DM + k0 + hi * 8;
#pragma unroll
        for (int t = 0; t < 16; ++t) {
            f16x8 b = *(const f16x8*)(wp + (size_t)t * 16 * DM);
            acc[t] = mfma16(a, b, acc[t]);
        }
    }
#pragma unroll
    for (int t = 0; t < 16; ++t) {
        int col = colbase + t * 16 + lo;
        float bv = bias[col];
        int hh = col >> 6, dh = col & 63;
#pragma unroll
        for (int r = 0; r < 4; ++r) {
            int row = rowbase + hi * 4 + r;
            int bi = row >> 11;          // / SEQ
            int ss = row & (SEQ - 1);
            float v = (acc[t][r] + bv) * scale;
            size_t dst;
            if (mode == 2)
                dst = (((size_t)(bi * NH + hh) * DH + dh) * SEQ + ss);
            else
                dst = (((size_t)(bi * NH + hh) * SEQ + ss) * DH + dh);
            out[dst] = (f16)v;
        }
    }
}

// ---------------- fused flash attention ----------------
// grid: (SEQ/64, BB*NH), block 256. Each wave: 16 q-rows, streams all keys.
__global__ __launch_bounds__(256) void attn_kernel(
    const f16* __restrict__ q16, const f16* __restrict__ k16,
    const f16* __restrict__ v16, const int* __restrict__ mask,
    f16* __restrict__ ctx16) {
    const int lane = threadIdx.x & 63;
    const int wave = threadIdx.x >> 6;
    const int lo = lane & 15, hi = lane >> 4;
    const int bh = blockIdx.y;
    const int b = bh >> 4, h = bh & 15;
    const int q0 = blockIdx.x * 64 + wave * 16;

    const f16* qp = q16 + (size_t)bh * SEQ * DH;
    const f16* kp = k16 + (size_t)bh * SEQ * DH;
    const f16* vp = v16 + (size_t)bh * DH * SEQ;
    const int* mp = mask + b * SEQ;

    f16x8 qa0 = *(const f16x8*)(qp + (size_t)(q0 + lo) * DH + hi * 8);
    f16x8 qa1 = *(const f16x8*)(qp + (size_t)(q0 + lo) * DH + 32 + hi * 8);

    f32x4 ctx[4];
#pragma unroll
    for (int dt = 0; dt < 4; ++dt) ctx[dt] = (f32x4){0.f, 0.f, 0.f, 0.f};
    float m[4], l[4];
#pragma unroll
    for (int r = 0; r < 4; ++r) { m[r] = -1e30f; l[r] = 0.f; }

    __shared__ f16 plds[4][16][48];   // padded rows (96 B stride, 16B aligned)

    for (int kb = 0; kb < SEQ; kb += 32) {
        f32x4 s0 = (f32x4){0.f, 0.f, 0.f, 0.f};
        f32x4 s1 = (f32x4){0.f, 0.f, 0.f, 0.f};
        const f16* kpt = kp + (size_t)(kb + lo) * DH + hi * 8;
        f16x8 k0a = *(const f16x8*)(kpt);
        f16x8 k0b = *(const f16x8*)(kpt + 32);
        f16x8 k1a = *(const f16x8*)(kpt + 16 * DH);
        f16x8 k1b = *(const f16x8*)(kpt + 16 * DH + 32);
        s0 = mfma16(qa0, k0a, s0);
        s0 = mfma16(qa1, k0b, s0);
        s1 = mfma16(qa0, k1a, s1);
        s1 = mfma16(qa1, k1b, s1);

        if (mp[kb + lo] == 0) { s0[0] = s0[1] = s0[2] = s0[3] = -1e9f; }
        if (mp[kb + 16 + lo] == 0) { s1[0] = s1[1] = s1[2] = s1[3] = -1e9f; }

        float tm[4], p0[4], p1[4], ts[4], sc[4];
#pragma unroll
        for (int r = 0; r < 4; ++r) tm[r] = fmaxf(s0[r], s1[r]);
#pragma unroll
        for (int off = 1; off < 16; off <<= 1)
#pragma unroll
            for (int r = 0; r < 4; ++r)
                tm[r] = fmaxf(tm[r], __shfl_xor(tm[r], off));
#pragma unroll
        for (int r = 0; r < 4; ++r) {
            float mn = fmaxf(m[r], tm[r]);
            sc[r] = __expf(m[r] - mn);
            m[r] = mn;
            p0[r] = __expf(s0[r] - mn);
            p1[r] = __expf(s1[r] - mn);
            ts[r] = p0[r] + p1[r];
        }
#pragma unroll
        for (int off = 1; off < 16; off <<= 1)
#pragma unroll
            for (int r = 0; r < 4; ++r)
                ts[r] += __shfl_xor(ts[r], off);
#pragma unroll
        for (int r = 0; r < 4; ++r) l[r] = l[r] * sc[r] + ts[r];
#pragma unroll
        for (int dt = 0; dt < 4; ++dt)
#pragma unroll
            for (int r = 0; r < 4; ++r) ctx[dt][r] *= sc[r];

#pragma unroll
        for (int r = 0; r < 4; ++r) {
            plds[wave][hi * 4 + r][lo] = (f16)p0[r];
            plds[wave][hi * 4 + r][16 + lo] = (f16)p1[r];
        }
        f16x8 pa = *(const f16x8*)&plds[wave][lo][hi * 8];
#pragma unroll
        for (int dt = 0; dt < 4; ++dt) {
            f16x8 vb = *(const f16x8*)(vp + (size_t)(dt * 16 + lo) * SEQ + kb + hi * 8);
            ctx[dt] = mfma16(pa, vb, ctx[dt]);
        }
    }

#pragma unroll
    for (int dt = 0; dt < 4; ++dt)
#pragma unroll
        for (int r = 0; r < 4; ++r) {
            float val = ctx[dt][r] / l[r];
            int ss = q0 + hi * 4 + r;
            int col = h * DH + dt * 16 + lo;
            ctx16[((size_t)(b * SEQ + ss)) * DM + col] = (f16)val;
        }
}

// ---------------- output projection + bias + residual ----------------
__global__ __launch_bounds__(256) void oproj_kernel(
    const f16* __restrict__ ctx16, const f16* __restrict__ W,
    const float* __restrict__ bo, const float* __restrict__ Qin,
    float* __restrict__ out) {
    const int lane = threadIdx.x & 63;
    const int wave = threadIdx.x >> 6;
    const int lo = lane & 15, hi = lane >> 4;
    const int rowbase = blockIdx.x * 64 + wave * 16;
    const int colbase = blockIdx.y * 256;

    f32x4 acc[16];
#pragma unroll
    for (int t = 0; t < 16; ++t) acc[t] = (f32x4){0.f, 0.f, 0.f, 0.f};

    const f16* ap = ctx16 + (size_t)(rowbase + lo) * DM + hi * 8;
    for (int k0 = 0; k0 < DM; k0 += 32) {
        f16x8 a = *(const f16x8*)(ap);
        ap += 32;
        const f16* wp = W + (size_t)(colbase + lo) * DM + k0 + hi * 8;
#pragma unroll
        for (int t = 0; t < 16; ++t) {
            f16x8 b = *(const f16x8*)(wp + (size_t)t * 16 * DM);
            acc[t] = mfma16(a, b, acc[t]);
        }
    }
#pragma unroll
    for (int t = 0; t < 16; ++t) {
        int col = colbase + t * 16 + lo;
        float bv = bo[col];
#pragma unroll
        for (int r = 0; r < 4; ++r) {
            int row = rowbase + hi * 4 + r;
            size_t idx = (size_t)row * DM + col;
            out[idx] = acc[t][r] + bv + Qin[idx];
        }
    }
}

// ---------------- in-place LayerNorm ----------------
__global__ __launch_bounds__(256) void ln_kernel(
    float* __restrict__ x, const float* __restrict__ gamma,
    const float* __restrict__ beta) {
    const int lane = threadIdx.x & 63;
    const int wave = threadIdx.x >> 6;
    const int row = blockIdx.x * 4 + wave;
    float* rp = x + (size_t)row * DM;

    float4 v[4];
#pragma unroll
    for (int j = 0; j < 4; ++j) v[j] = ((const float4*)rp)[lane + 64 * j];

    float sum = 0.f;
#pragma unroll
    for (int j = 0; j < 4; ++j) sum += v[j].x + v[j].y + v[j].z + v[j].w;
#pragma unroll
    for (int off = 1; off < 64; off <<= 1) sum += __shfl_xor(sum, off);
    float mean = sum * (1.f / DM);

    float vs = 0.f;
#pragma unroll
    for (int j = 0; j < 4; ++j) {
        float dx = v[j].x - mean, dy = v[j].y - mean, dz = v[j].z - mean, dw = v[j].w - mean;
        vs += dx * dx + dy * dy + dz * dz + dw * dw;
    }
#pragma unroll
    for (int off = 1; off < 64; off <<= 1) vs += __shfl_xor(vs, off);
    float rstd = rsqrtf(vs * (1.f / DM) + 1e-5f);

#pragma unroll
    for (int j = 0; j < 4; ++j) {
        int idx = lane + 64 * j;
        float4 g = ((const float4*)gamma)[idx];
        float4 bt = ((const float4*)beta)[idx];
        float4 o;
        o.x = (v[j].x - mean) * rstd * g.x + bt.x;
        o.y = (v[j].y - mean) * rstd * g.y + bt.y;
        o.z = (v[j].z - mean) * rstd * g.z + bt.z;
        o.w = (v[j].w - mean) * rstd * g.w + bt.w;
        ((float4*)rp)[idx] = o;
    }
}

extern "C" void kernel_launch(void* const* d_in, const int* in_sizes, int n_in,
                              void* d_out, int out_size, void* d_ws, size_t ws_size,
                              hipStream_t stream) {
    const float* Q    = (const float*)d_in[0];
    const float* K    = (const float*)d_in[1];
    const float* V    = (const float*)d_in[2];
    const int*   mask = (const int*)d_in[3];
    const float* Wq   = (const float*)d_in[4];
    const float* bq   = (const float*)d_in[5];
    const float* Wk   = (const float*)d_in[6];
    const float* bk   = (const float*)d_in[7];
    const float* Wv   = (const float*)d_in[8];
    const float* bv   = (const float*)d_in[9];
    const float* Wo   = (const float*)d_in[10];
    const float* bo   = (const float*)d_in[11];
    const float* gamma = (const float*)d_in[12];
    const float* beta  = (const float*)d_in[13];
    float* out = (float*)d_out;

    char* ws = (char*)d_ws;
    const size_t MB = 1024 * 1024;
    f16* wq16 = (f16*)(ws + 0 * MB);
    f16* wk16 = (f16*)(ws + 2 * MB);
    f16* wv16 = (f16*)(ws + 4 * MB);
    f16* wo16 = (f16*)(ws + 6 * MB);
    f16* q16  = (f16*)(ws + 8 * MB);
    f16* k16  = (f16*)(ws + 24 * MB);
    f16* v16t = (f16*)(ws + 40 * MB);
    f16* c16  = (f16*)(ws + 56 * MB);   // total 72 MB

    cvt_weights<<<dim3(DM * DM / (256 * 4)), dim3(256), 0, stream>>>(
        Wq, Wk, Wv, Wo, wq16, wk16, wv16, wo16);

    const float qscale = 0.125f;   // 1/sqrt(DH)
    proj_kernel<<<dim3(ROWS / 64, DM / 256), dim3(256), 0, stream>>>(
        Q, wq16, bq, q16, qscale, 0);
    proj_kernel<<<dim3(ROWS / 64, DM / 256), dim3(256), 0, stream>>>(
        K, wk16, bk, k16, 1.0f, 0);
    proj_kernel<<<dim3(ROWS / 64, DM / 256), dim3(256), 0, stream>>>(
        V, wv16, bv, v16t, 1.0f, 2);

    attn_kernel<<<dim3(SEQ / 64, BB * NH), dim3(256), 0, stream>>>(
        q16, k16, v16t, mask, c16);

    oproj_kernel<<<dim3(ROWS / 64, DM / 256), dim3(256), 0, stream>>>(
        c16, wo16, bo, Q, out);

    ln_kernel<<<dim3(ROWS / 4), dim3(256), 0, stream>>>(out, gamma, beta);
}

// Round 3
// 818.118 us; speedup vs baseline: 1.2408x; 1.2408x over previous
//
#include <hip/hip_runtime.h>

#define SEQ 2048
#define BB 4
#define DM 1024
#define NH 16
#define DH 64
#define ROWS (BB*SEQ)

typedef _Float16 f16;
typedef _Float16 f16x8 __attribute__((ext_vector_type(8)));
typedef _Float16 f16x4 __attribute__((ext_vector_type(4)));
typedef float f32x4 __attribute__((ext_vector_type(4)));
typedef float f32x16 __attribute__((ext_vector_type(16)));
typedef unsigned u32x4 __attribute__((ext_vector_type(4)));

__device__ __forceinline__ f32x4 mfma16(f16x8 a, f16x8 b, f32x4 c) {
    return __builtin_amdgcn_mfma_f32_16x16x32_f16(a, b, c, 0, 0, 0);
}
__device__ __forceinline__ f32x16 mfma32(f16x8 a, f16x8 b, f32x16 c) {
    return __builtin_amdgcn_mfma_f32_32x32x16_f16(a, b, c, 0, 0, 0);
}
__device__ __forceinline__ unsigned pkh(float a, float b) {
    auto h = __builtin_amdgcn_cvt_pkrtz(a, b);   // __fp16 ext_vector(2)
    return __builtin_bit_cast(unsigned, h);
}

// ---------------- weight conversion fp32 -> f16 ----------------
__global__ __launch_bounds__(256) void cvt_weights(
    const float* __restrict__ wq, const float* __restrict__ wk,
    const float* __restrict__ wv, const float* __restrict__ wo,
    f16* __restrict__ oq, f16* __restrict__ ok,
    f16* __restrict__ ov, f16* __restrict__ oo) {
    int i = (blockIdx.x * 256 + threadIdx.x) * 4;
    float4 a = *(const float4*)(wq + i);
    float4 b = *(const float4*)(wk + i);
    float4 c = *(const float4*)(wv + i);
    float4 d = *(const float4*)(wo + i);
    f16x4 va = { (f16)a.x, (f16)a.y, (f16)a.z, (f16)a.w };
    f16x4 vb = { (f16)b.x, (f16)b.y, (f16)b.z, (f16)b.w };
    f16x4 vc = { (f16)c.x, (f16)c.y, (f16)c.z, (f16)c.w };
    f16x4 vd = { (f16)d.x, (f16)d.y, (f16)d.z, (f16)d.w };
    *(f16x4*)(oq + i) = va;
    *(f16x4*)(ok + i) = vb;
    *(f16x4*)(ov + i) = vc;
    *(f16x4*)(oo + i) = vd;
}

// ---------------- QKV projection GEMM ----------------
// mode 0: write [b][h][s][dh]   (q, k)
// mode 2: write [b][h][dh][s]   (v transposed)
__global__ __launch_bounds__(256) void proj_kernel(
    const float* __restrict__ X, const f16* __restrict__ W,
    const float* __restrict__ bias, f16* __restrict__ out,
    float scale, int mode) {
    const int lane = threadIdx.x & 63;
    const int wave = threadIdx.x >> 6;
    const int lo = lane & 15, hi = lane >> 4;
    const int rowbase = blockIdx.x * 64 + wave * 16;
    const int colbase = blockIdx.y * 256;

    f32x4 acc[16];
#pragma unroll
    for (int t = 0; t < 16; ++t) acc[t] = (f32x4){0.f, 0.f, 0.f, 0.f};

    const float* ap = X + (size_t)(rowbase + lo) * DM + hi * 8;
    for (int k0 = 0; k0 < DM; k0 += 32) {
        float4 a0 = *(const float4*)(ap);
        float4 a1 = *(const float4*)(ap + 4);
        ap += 32;
        f16x8 a;
        a[0] = (f16)a0.x; a[1] = (f16)a0.y; a[2] = (f16)a0.z; a[3] = (f16)a0.w;
        a[4] = (f16)a1.x; a[5] = (f16)a1.y; a[6] = (f16)a1.z; a[7] = (f16)a1.w;
        const f16* wp = W + (size_t)(colbase + lo) * DM + k0 + hi * 8;
#pragma unroll
        for (int t = 0; t < 16; ++t) {
            f16x8 b = *(const f16x8*)(wp + (size_t)t * 16 * DM);
            acc[t] = mfma16(a, b, acc[t]);
        }
    }
#pragma unroll
    for (int t = 0; t < 16; ++t) {
        int col = colbase + t * 16 + lo;
        float bv = bias[col];
        int hh = col >> 6, dh = col & 63;
#pragma unroll
        for (int r = 0; r < 4; ++r) {
            int row = rowbase + hi * 4 + r;
            int bi = row >> 11;
            int ss = row & (SEQ - 1);
            float v = (acc[t][r] + bv) * scale;
            size_t dst;
            if (mode == 2)
                dst = (((size_t)(bi * NH + hh) * DH + dh) * SEQ + ss);
            else
                dst = (((size_t)(bi * NH + hh) * SEQ + ss) * DH + dh);
            out[dst] = (f16)v;
        }
    }
}

// ---------------- fused flash attention (32x32 swapped-QK, in-register softmax) ----
// grid: (SEQ/128, BB*NH), block 256 (4 waves x 32 q-rows).
// Scores are pre-scaled by log2(e)/sqrt(DH) (folded into q16), softmax uses exp2.
__global__ __launch_bounds__(256) void attn_kernel(
    const f16* __restrict__ q16, const f16* __restrict__ k16,
    const f16* __restrict__ v16t, const int* __restrict__ mask,
    f16* __restrict__ out16) {
    const int lane = threadIdx.x & 63;
    const int wv = threadIdx.x >> 6;
    const int lo = lane & 31;       // q-row (B frag / ctx col) / key row (K A-frag) / d row (V A-frag)
    const int hw = lane >> 5;       // wave half
    const int bh = blockIdx.y;
    const int b = bh >> 4, hd = bh & 15;
    const int q0 = blockIdx.x * 128 + wv * 32;

    const f16* qp = q16 + ((size_t)bh * SEQ + q0 + lo) * DH + hw * 8;
    const f16* kp = k16 + (size_t)bh * SEQ * DH;
    const f16* vp = v16t + (size_t)bh * DH * SEQ;
    const int* mp = mask + b * SEQ;

    f16x8 qb[4];
#pragma unroll
    for (int c = 0; c < 4; ++c) qb[c] = *(const f16x8*)(qp + c * 16);

    f32x16 ctx0, ctx1;
#pragma unroll
    for (int i = 0; i < 16; ++i) { ctx0[i] = 0.f; ctx1[i] = 0.f; }
    float m = -3e38f, l = 0.f;

    const f16* kit = kp + (size_t)lo * DH + hw * 8;
    const f16* vit = vp + (size_t)lo * SEQ + hw * 8;
    const int* mit = mp + lo;

    for (int kb = 0; kb < SEQ; kb += 64) {
        // ---- K fragments (A operand): K[kb+kt*32+lo][c*16+hw*8 ..] ----
        const f16* kpt = kit + (size_t)kb * DH;
        f16x8 ka00 = *(const f16x8*)(kpt);
        f16x8 ka01 = *(const f16x8*)(kpt + 16);
        f16x8 ka02 = *(const f16x8*)(kpt + 32);
        f16x8 ka03 = *(const f16x8*)(kpt + 48);
        f16x8 ka10 = *(const f16x8*)(kpt + 32 * DH);
        f16x8 ka11 = *(const f16x8*)(kpt + 32 * DH + 16);
        f16x8 ka12 = *(const f16x8*)(kpt + 32 * DH + 32);
        f16x8 ka13 = *(const f16x8*)(kpt + 32 * DH + 48);

        f32x16 st0, st1;
#pragma unroll
        for (int i = 0; i < 16; ++i) { st0[i] = 0.f; st1[i] = 0.f; }
        st0 = mfma32(ka00, qb[0], st0);
        st0 = mfma32(ka01, qb[1], st0);
        st0 = mfma32(ka02, qb[2], st0);
        st0 = mfma32(ka03, qb[3], st0);
        st1 = mfma32(ka10, qb[0], st1);
        st1 = mfma32(ka11, qb[1], st1);
        st1 = mfma32(ka12, qb[2], st1);
        st1 = mfma32(ka13, qb[3], st1);

        // ---- V fragments (A operand for ctx^T): V^T[dt*32+lo][kb+kt*32+c*16+hw*8 ..] ----
        const f16* vpt = vit + kb;
        f16x8 v000 = *(const f16x8*)(vpt);
        f16x8 v001 = *(const f16x8*)(vpt + 16);
        f16x8 v010 = *(const f16x8*)(vpt + 32);
        f16x8 v011 = *(const f16x8*)(vpt + 48);
        f16x8 v100 = *(const f16x8*)(vpt + 32 * SEQ);
        f16x8 v101 = *(const f16x8*)(vpt + 32 * SEQ + 16);
        f16x8 v110 = *(const f16x8*)(vpt + 32 * SEQ + 32);
        f16x8 v111 = *(const f16x8*)(vpt + 32 * SEQ + 48);

        // ---- mask (key-only, (B,1,1,S)) ----
        unsigned bm0 = (unsigned)__ballot(mit[kb] != 0);
        unsigned bm1 = (unsigned)__ballot(mit[kb + 32] != 0);
        if (bm0 != 0xffffffffu) {
            unsigned bs = bm0 >> (hw * 4);
#pragma unroll
            for (int r = 0; r < 16; ++r)
                if (!((bs >> ((r & 3) + 8 * (r >> 2))) & 1)) st0[r] = -1e9f;
        }
        if (bm1 != 0xffffffffu) {
            unsigned bs = bm1 >> (hw * 4);
#pragma unroll
            for (int r = 0; r < 16; ++r)
                if (!((bs >> ((r & 3) + 8 * (r >> 2))) & 1)) st1[r] = -1e9f;
        }

        // ---- online softmax (lane-local row; combine across wave halves) ----
        float tm = fmaxf(st0[0], st1[0]);
#pragma unroll
        for (int i = 1; i < 16; ++i) tm = fmaxf(tm, fmaxf(st0[i], st1[i]));
        tm = fmaxf(tm, __shfl_xor(tm, 32));

        if (!__all(tm <= m)) {          // defer-max: rescale only on new max
            float mn = fmaxf(m, tm);
            float sc = exp2f(m - mn);
            l *= sc;
#pragma unroll
            for (int i = 0; i < 16; ++i) { ctx0[i] *= sc; ctx1[i] *= sc; }
            m = mn;
        }
        float ts = 0.f;
#pragma unroll
        for (int i = 0; i < 16; ++i) { st0[i] = exp2f(st0[i] - m); ts += st0[i]; }
#pragma unroll
        for (int i = 0; i < 16; ++i) { st1[i] = exp2f(st1[i] - m); ts += st1[i]; }
        ts += __shfl_xor(ts, 32);
        l += ts;

        // ---- P -> B-fragment (pack + half-wave exchange), PV MFMAs ----
#define PV_TILE(ST, V0C0, V0C1, V1C0, V1C1)                                       \
        {                                                                          \
            unsigned w0 = pkh(ST[0], ST[1]),   w1 = pkh(ST[2], ST[3]);             \
            unsigned w2 = pkh(ST[4], ST[5]),   w3 = pkh(ST[6], ST[7]);             \
            unsigned w4 = pkh(ST[8], ST[9]),   w5 = pkh(ST[10], ST[11]);           \
            unsigned w6 = pkh(ST[12], ST[13]), w7 = pkh(ST[14], ST[15]);           \
            {                                                                      \
                unsigned s0 = __shfl_xor(w2, 32), s1 = __shfl_xor(w3, 32);         \
                unsigned s2 = __shfl_xor(w0, 32), s3 = __shfl_xor(w1, 32);         \
                u32x4 t = { hw ? s0 : w0, hw ? s1 : w1,                            \
                            hw ? w2 : s2, hw ? w3 : s3 };                          \
                f16x8 pb = __builtin_bit_cast(f16x8, t);                           \
                ctx0 = mfma32(V0C0, pb, ctx0);                                     \
                ctx1 = mfma32(V1C0, pb, ctx1);                                     \
            }                                                                      \
            {                                                                      \
                unsigned s0 = __shfl_xor(w6, 32), s1 = __shfl_xor(w7, 32);         \
                unsigned s2 = __shfl_xor(w4, 32), s3 = __shfl_xor(w5, 32);         \
                u32x4 t = { hw ? s0 : w4, hw ? s1 : w5,                            \
                            hw ? w6 : s2, hw ? w7 : s3 };                          \
                f16x8 pb = __builtin_bit_cast(f16x8, t);                           \
                ctx0 = mfma32(V0C1, pb, ctx0);                                     \
                ctx1 = mfma32(V1C1, pb, ctx1);                                     \
            }                                                                      \
        }
        PV_TILE(st0, v000, v001, v100, v101)
        PV_TILE(st1, v010, v011, v110, v111)
#undef PV_TILE
    }

    // ---- epilogue: divide by l, transpose via LDS, coalesced f16 stores ----
    float rl = 1.0f / l;
    __shared__ f16 tb[4][32][66];
#pragma unroll
    for (int u = 0; u < 8; ++u) {
        int d0 = 2 * (u & 1) + 8 * (u >> 1) + 4 * hw;
        unsigned pw0 = pkh(ctx0[2 * u] * rl, ctx0[2 * u + 1] * rl);
        unsigned pw1 = pkh(ctx1[2 * u] * rl, ctx1[2 * u + 1] * rl);
        *(unsigned*)&tb[wv][lo][d0] = pw0;
        *(unsigned*)&tb[wv][lo][32 + d0] = pw1;
    }
#pragma unroll
    for (int it = 0; it < 4; ++it) {
        int r = it * 8 + (lane >> 3);
        const unsigned* src = (const unsigned*)&tb[wv][r][0];
        int cc = (lane & 7) * 4;
        u32x4 t = { src[cc], src[cc + 1], src[cc + 2], src[cc + 3] };
        f16x8 vvv = __builtin_bit_cast(f16x8, t);
        *(f16x8*)(out16 + ((size_t)(b * SEQ) + q0 + r) * DM + hd * 64 + (lane & 7) * 8) = vvv;
    }
}

// ---------------- output projection + bias + residual ----------------
__global__ __launch_bounds__(256) void oproj_kernel(
    const f16* __restrict__ ctx16, const f16* __restrict__ W,
    const float* __restrict__ bo, const float* __restrict__ Qin,
    float* __restrict__ out) {
    const int lane = threadIdx.x & 63;
    const int wave = threadIdx.x >> 6;
    const int lo = lane & 15, hi = lane >> 4;
    const int rowbase = blockIdx.x * 64 + wave * 16;
    const int colbase = blockIdx.y * 256;

    f32x4 acc[16];
#pragma unroll
    for (int t = 0; t < 16; ++t) acc[t] = (f32x4){0.f, 0.f, 0.f, 0.f};

    const f16* ap = ctx16 + (size_t)(rowbase + lo) * DM + hi * 8;
    for (int k0 = 0; k0 < DM; k0 += 32) {
        f16x8 a = *(const f16x8*)(ap);
        ap += 32;
        const f16* wp = W + (size_t)(colbase + lo) * DM + k0 + hi * 8;
#pragma unroll
        for (int t = 0; t < 16; ++t) {
            f16x8 b = *(const f16x8*)(wp + (size_t)t * 16 * DM);
            acc[t] = mfma16(a, b, acc[t]);
        }
    }
#pragma unroll
    for (int t = 0; t < 16; ++t) {
        int col = colbase + t * 16 + lo;
        float bv = bo[col];
#pragma unroll
        for (int r = 0; r < 4; ++r) {
            int row = rowbase + hi * 4 + r;
            size_t idx = (size_t)row * DM + col;
            out[idx] = acc[t][r] + bv + Qin[idx];
        }
    }
}

// ---------------- in-place LayerNorm ----------------
__global__ __launch_bounds__(256) void ln_kernel(
    float* __restrict__ x, const float* __restrict__ gamma,
    const float* __restrict__ beta) {
    const int lane = threadIdx.x & 63;
    const int wave = threadIdx.x >> 6;
    const int row = blockIdx.x * 4 + wave;
    float* rp = x + (size_t)row * DM;

    float4 v[4];
#pragma unroll
    for (int j = 0; j < 4; ++j) v[j] = ((const float4*)rp)[lane + 64 * j];

    float sum = 0.f;
#pragma unroll
    for (int j = 0; j < 4; ++j) sum += v[j].x + v[j].y + v[j].z + v[j].w;
#pragma unroll
    for (int off = 1; off < 64; off <<= 1) sum += __shfl_xor(sum, off);
    float mean = sum * (1.f / DM);

    float vs = 0.f;
#pragma unroll
    for (int j = 0; j < 4; ++j) {
        float dx = v[j].x - mean, dy = v[j].y - mean, dz = v[j].z - mean, dw = v[j].w - mean;
        vs += dx * dx + dy * dy + dz * dz + dw * dw;
    }
#pragma unroll
    for (int off = 1; off < 64; off <<= 1) vs += __shfl_xor(vs, off);
    float rstd = rsqrtf(vs * (1.f / DM) + 1e-5f);

#pragma unroll
    for (int j = 0; j < 4; ++j) {
        int idx = lane + 64 * j;
        float4 g = ((const float4*)gamma)[idx];
        float4 bt = ((const float4*)beta)[idx];
        float4 o;
        o.x = (v[j].x - mean) * rstd * g.x + bt.x;
        o.y = (v[j].y - mean) * rstd * g.y + bt.y;
        o.z = (v[j].z - mean) * rstd * g.z + bt.z;
        o.w = (v[j].w - mean) * rstd * g.w + bt.w;
        ((float4*)rp)[idx] = o;
    }
}

extern "C" void kernel_launch(void* const* d_in, const int* in_sizes, int n_in,
                              void* d_out, int out_size, void* d_ws, size_t ws_size,
                              hipStream_t stream) {
    const float* Q    = (const float*)d_in[0];
    const float* K    = (const float*)d_in[1];
    const float* V    = (const float*)d_in[2];
    const int*   mask = (const int*)d_in[3];
    const float* Wq   = (const float*)d_in[4];
    const float* bq   = (const float*)d_in[5];
    const float* Wk   = (const float*)d_in[6];
    const float* bk   = (const float*)d_in[7];
    const float* Wv   = (const float*)d_in[8];
    const float* bv   = (const float*)d_in[9];
    const float* Wo   = (const float*)d_in[10];
    const float* bo   = (const float*)d_in[11];
    const float* gamma = (const float*)d_in[12];
    const float* beta  = (const float*)d_in[13];
    float* out = (float*)d_out;

    char* ws = (char*)d_ws;
    const size_t MB = 1024 * 1024;
    f16* wq16 = (f16*)(ws + 0 * MB);
    f16* wk16 = (f16*)(ws + 2 * MB);
    f16* wv16 = (f16*)(ws + 4 * MB);
    f16* wo16 = (f16*)(ws + 6 * MB);
    f16* q16  = (f16*)(ws + 8 * MB);
    f16* k16  = (f16*)(ws + 24 * MB);
    f16* v16t = (f16*)(ws + 40 * MB);
    f16* c16  = (f16*)(ws + 56 * MB);

    cvt_weights<<<dim3(DM * DM / (256 * 4)), dim3(256), 0, stream>>>(
        Wq, Wk, Wv, Wo, wq16, wk16, wv16, wo16);

    // fold 1/sqrt(DH) * log2(e) into q so attention can use exp2
    const float qscale = 0.125f * 1.44269504f;
    proj_kernel<<<dim3(ROWS / 64, DM / 256), dim3(256), 0, stream>>>(
        Q, wq16, bq, q16, qscale, 0);
    proj_kernel<<<dim3(ROWS / 64, DM / 256), dim3(256), 0, stream>>>(
        K, wk16, bk, k16, 1.0f, 0);
    proj_kernel<<<dim3(ROWS / 64, DM / 256), dim3(256), 0, stream>>>(
        V, wv16, bv, v16t, 1.0f, 2);

    attn_kernel<<<dim3(SEQ / 128, BB * NH), dim3(256), 0, stream>>>(
        q16, k16, v16t, mask, c16);

    oproj_kernel<<<dim3(ROWS / 64, DM / 256), dim3(256), 0, stream>>>(
        c16, wo16, bo, Q, out);

    ln_kernel<<<dim3(ROWS / 4), dim3(256), 0, stream>>>(out, gamma, beta);
}